// Round 6
// baseline (322.754 us; speedup 1.0000x reference)
//
#include <hip/hip_runtime.h>

#define NN     256
#define NF     127
#define DIM    128
#define NH     8
#define DH     64
#define INNER  512
#define DEPTH  6
#define NB     512
#define ATTN_SCALE 0.125f
#define LN_EPS 1e-5f

__device__ __forceinline__ float wred_sum(float v){
#pragma unroll
  for(int o=32;o;o>>=1) v += __shfl_xor(v,o);
  return v;
}
__device__ __forceinline__ float wred_max(float v){
#pragma unroll
  for(int o=32;o;o>>=1) v = fmaxf(v,__shfl_xor(v,o));
  return v;
}
// block = 512 threads (8 waves). sred must have >= 16 floats.
// dual block reduction: returns (sum v0, sum v1) in one barrier pair.
__device__ __forceinline__ float2 block_sum2(float v0, float v1, float* sred, int t){
  v0 = wred_sum(v0); v1 = wred_sum(v1);
  __syncthreads();
  if((t&63)==0){ sred[t>>6]=v0; sred[8+(t>>6)]=v1; }
  __syncthreads();
  float s0=0.f, s1=0.f;
#pragma unroll
  for(int w=0; w<8; w++){ s0 += sred[w]; s1 += sred[8+w]; }
  return make_float2(s0,s1);
}

// Dual LayerNorm: in0/in1 (LDS, DIM) -> out0/out1. All 512 threads call.
__device__ __forceinline__ void dev_ln2(const float* in0, const float* in1,
                                        float* out0, float* out1,
                                        const float* g, const float* b,
                                        float* sred, int t){
  float v0 = (t<DIM)? in0[t] : 0.f;
  float v1 = (t<DIM)? in1[t] : 0.f;
  float2 m = block_sum2(v0,v1,sred,t);
  float m0 = m.x*(1.f/DIM), m1 = m.y*(1.f/DIM);
  float d0 = (t<DIM)? (v0-m0) : 0.f;
  float d1 = (t<DIM)? (v1-m1) : 0.f;
  float2 vv = block_sum2(d0*d0,d1*d1,sred,t);
  float rs0 = rsqrtf(vv.x*(1.f/DIM) + LN_EPS);
  float rs1 = rsqrtf(vv.y*(1.f/DIM) + LN_EPS);
  if(t<DIM){
    float gg = g[t], bb = b[t];
    out0[t] = d0*rs0*gg + bb;
    out1[t] = d1*rs1*gg + bb;
  }
  __syncthreads();
}

// Q/K/V for rows i0,i0+1 from xs0/xs1 (LDS). Weight float4 loaded ONCE for both
// rows. q row-major, k transposed [o][j] (float2-paired rows), v row-major.
// be folded into k and v. scratch: 4096-float LDS.
__device__ __forceinline__ void dev_qkv2(const float* xs0, const float* xs1, int i0,
    const float* Wq, const float* bq, const float* Wkv, const float* bkv,
    const float* be, float* qg, float* kT, float* vg, float* scratch, int t){
  // ---- q: 128 col-groups(4) x 4 row-quarters(32) ----
  {
    const int cg4 = (t&127)*4, rq = t>>7;
    float4 a0 = make_float4(0.f,0.f,0.f,0.f);
    float4 a1 = make_float4(0.f,0.f,0.f,0.f);
#pragma unroll
    for(int f=rq*32; f<rq*32+32; f++){
      float x0 = xs0[f], x1 = xs1[f];
      float4 w = *(const float4*)(Wq + f*INNER + cg4);
      a0.x=fmaf(x0,w.x,a0.x); a0.y=fmaf(x0,w.y,a0.y);
      a0.z=fmaf(x0,w.z,a0.z); a0.w=fmaf(x0,w.w,a0.w);
      a1.x=fmaf(x1,w.x,a1.x); a1.y=fmaf(x1,w.y,a1.y);
      a1.z=fmaf(x1,w.z,a1.z); a1.w=fmaf(x1,w.w,a1.w);
    }
    *(float4*)(scratch + rq*INNER + cg4)        = a0;
    *(float4*)(scratch + 2048 + rq*INNER + cg4) = a1;
  }
  __syncthreads();
  {
    float bqt = bq[t];
    qg[i0*INNER+t]     = bqt + scratch[t] + scratch[INNER+t]
                             + scratch[2*INNER+t] + scratch[3*INNER+t];
    qg[(i0+1)*INNER+t] = bqt + scratch[2048+t] + scratch[2048+INNER+t]
                             + scratch[2048+2*INNER+t] + scratch[2048+3*INNER+t];
  }
  __syncthreads();
  // ---- kv: 256 col-groups(4) x 2 row-halves(64) ----
  {
    const int cg4 = (t&255)*4, rh = t>>8;
    float4 a0 = make_float4(0.f,0.f,0.f,0.f);
    float4 a1 = make_float4(0.f,0.f,0.f,0.f);
#pragma unroll 8
    for(int f=rh*64; f<rh*64+64; f++){
      float x0 = xs0[f], x1 = xs1[f];
      float4 w = *(const float4*)(Wkv + f*(2*INNER) + cg4);
      a0.x=fmaf(x0,w.x,a0.x); a0.y=fmaf(x0,w.y,a0.y);
      a0.z=fmaf(x0,w.z,a0.z); a0.w=fmaf(x0,w.w,a0.w);
      a1.x=fmaf(x1,w.x,a1.x); a1.y=fmaf(x1,w.y,a1.y);
      a1.z=fmaf(x1,w.z,a1.z); a1.w=fmaf(x1,w.w,a1.w);
    }
    *(float4*)(scratch + rh*1024 + cg4)        = a0;
    *(float4*)(scratch + 2048 + rh*1024 + cg4) = a1;
  }
  __syncthreads();
#pragma unroll
  for(int cc=0; cc<2; cc++){
    int c = t + cc*512;
    float bk = bkv[c];
    float s0 = scratch[c]      + scratch[1024+c]      + bk;
    float s1 = scratch[2048+c] + scratch[2048+1024+c] + bk;
    if(c < INNER){
      float bec = be[c];
      *(float2*)(kT + c*NN + i0) = make_float2(s0+bec, s1+bec);
    } else {
      float bec = be[c-INNER];
      vg[i0*INNER+c-INNER]     = s0 + bec;
      vg[(i0+1)*INNER+c-INNER] = s1 + bec;
    }
  }
  __syncthreads();
}

// ---- fused node-init + LN1 + QKV for layer 0 (2 rows/block) ----
__global__ __launch_bounds__(512) void k_qkv0(const float* atom_emb, const float* noise,
    float* nodes,
    const float* ln1_g, const float* ln1_b,
    const float* Wq, const float* bq, const float* Wkv, const float* bkv, const float* be,
    float* qg, float* kT, float* vg){
  __shared__ float nd0[DIM], nd1[DIM], xs0[DIM], xs1[DIM], sred[16], scratch[4096];
  int t = threadIdx.x, i0 = blockIdx.x*2;
  if(t<DIM){
    float nz = noise[0];
    float v0 = (t<NF)? atom_emb[i0*NF+t]     : nz;
    float v1 = (t<NF)? atom_emb[(i0+1)*NF+t] : nz;
    nd0[t]=v0; nd1[t]=v1;
    nodes[i0*DIM+t]=v0; nodes[(i0+1)*DIM+t]=v1;
  }
  __syncthreads();
  dev_ln2(nd0, nd1, xs0, xs1, ln1_g, ln1_b, sred, t);
  dev_qkv2(xs0, xs1, i0, Wq, bq, Wkv, bkv, be, qg, kT, vg, scratch, t);
}

// ---- fused per-layer kernel, 2 rows/block ----
__global__ __launch_bounds__(512) void k_layer(
    float* nodes, const float* qg, const float* kT, const float* vg,
    float* qg_n, float* kT_n, float* vg_n,
    const int* bonds, const float* coords,
    const float* We,
    const float* Wo, const float* bo, const float* Wg1,
    const float* ln2_g, const float* ln2_b,
    const float* W1, const float* b1, const float* W2, const float* b2,
    const float* Wg2,
    const float* ln1_g_n, const float* ln1_b_n,
    const float* Wq_n, const float* bq_n, const float* Wkv_n, const float* bkv_n,
    const float* be_n, int has_next)
{
  __shared__ float nd0[DIM], nd1[DIM], xs0[DIM], xs1[DIM];
  __shared__ float qs0[INNER], qs1[INNER], ao0[INNER], ao1[INNER];
  __shared__ float o1280[DIM], o1281[DIM];
  __shared__ float eL0[NN*3], eL1[NN*3];
  __shared__ float scratch[4096];          // aliased: aW (attn) / redS (GEMMs)
  __shared__ float sred[16], qWe[2*NH*3];
  const int t = threadIdx.x, i0 = blockIdx.x*2, i1 = i0+1;

  if(t<DIM){ nd0[t] = nodes[i0*DIM+t]; nd1[t] = nodes[i1*DIM+t]; }
  qs0[t] = qg[i0*INNER+t]; qs1[t] = qg[i1*INNER+t];
  // zero eL0/eL1 (768 floats each) -- exactly in bounds
  eL0[t] = 0.f; eL1[t] = 0.f;
  if(t<NN){ eL0[512+t] = 0.f; eL1[512+t] = 0.f; }
  __syncthreads();

  // build edge rows i0,i1 from bond list (duplicate writes carry identical values)
  {
    int bi = bonds[2*t], bj = bonds[2*t+1];
    if(bi==i0||bj==i0||bi==i1||bj==i1){
      float dx = coords[3*bi+0] - coords[3*bj+0];
      float dy = coords[3*bi+1] - coords[3*bj+1];
      float dz = coords[3*bi+2] - coords[3*bj+2];
      if(bi==i0){ eL0[bj*3+0]=dx;  eL0[bj*3+1]=dy;  eL0[bj*3+2]=dz;  }
      if(bj==i0){ eL0[bi*3+0]=-dx; eL0[bi*3+1]=-dy; eL0[bi*3+2]=-dz; }
      if(bi==i1){ eL1[bj*3+0]=dx;  eL1[bj*3+1]=dy;  eL1[bj*3+2]=dz;  }
      if(bj==i1){ eL1[bi*3+0]=-dx; eL1[bi*3+1]=-dy; eL1[bi*3+2]=-dz; }
    }
  }
  __syncthreads();

  if(t < 2*NH*3){            // qWe[r][h][c] = q_{i_r}[h-slice] . We[c, h-slice]
    int r = t/24, rem = t%24, h = rem/3, c = rem%3;
    const float* qsr = r? qs1 : qs0;
    float acc = 0.f;
    for(int d=0; d<DH; d++) acc = fmaf(qsr[h*DH+d], We[c*INNER + h*DH + d], acc);
    qWe[t] = acc;
  }
  __syncthreads();

  // ---- attention: wave w == head w, both rows. no block barriers inside ----
  {
    const int h = t>>6, l = t&63, j0 = 4*l;
    const float* kTh = kT + (h*DH)*NN;
    float4 sA = make_float4(0.f,0.f,0.f,0.f);
    float4 sB = make_float4(0.f,0.f,0.f,0.f);
#pragma unroll 8
    for(int o=0; o<DH; o++){
      float qa = qs0[h*DH+o], qb = qs1[h*DH+o];
      float4 kk = *(const float4*)(kTh + o*NN + j0);
      sA.x=fmaf(qa,kk.x,sA.x); sA.y=fmaf(qa,kk.y,sA.y);
      sA.z=fmaf(qa,kk.z,sA.z); sA.w=fmaf(qa,kk.w,sA.w);
      sB.x=fmaf(qb,kk.x,sB.x); sB.y=fmaf(qb,kk.y,sB.y);
      sB.z=fmaf(qb,kk.z,sB.z); sB.w=fmaf(qb,kk.w,sB.w);
    }
    float wa0=qWe[h*3+0],    wa1=qWe[h*3+1],    wa2=qWe[h*3+2];
    float wb0=qWe[24+h*3+0], wb1=qWe[24+h*3+1], wb2=qWe[24+h*3+2];
    sA.x += wa0*eL0[(j0+0)*3+0] + wa1*eL0[(j0+0)*3+1] + wa2*eL0[(j0+0)*3+2];
    sA.y += wa0*eL0[(j0+1)*3+0] + wa1*eL0[(j0+1)*3+1] + wa2*eL0[(j0+1)*3+2];
    sA.z += wa0*eL0[(j0+2)*3+0] + wa1*eL0[(j0+2)*3+1] + wa2*eL0[(j0+2)*3+2];
    sA.w += wa0*eL0[(j0+3)*3+0] + wa1*eL0[(j0+3)*3+1] + wa2*eL0[(j0+3)*3+2];
    sB.x += wb0*eL1[(j0+0)*3+0] + wb1*eL1[(j0+0)*3+1] + wb2*eL1[(j0+0)*3+2];
    sB.y += wb0*eL1[(j0+1)*3+0] + wb1*eL1[(j0+1)*3+1] + wb2*eL1[(j0+1)*3+2];
    sB.z += wb0*eL1[(j0+2)*3+0] + wb1*eL1[(j0+2)*3+1] + wb2*eL1[(j0+2)*3+2];
    sB.w += wb0*eL1[(j0+3)*3+0] + wb1*eL1[(j0+3)*3+1] + wb2*eL1[(j0+3)*3+2];
    sA.x*=ATTN_SCALE; sA.y*=ATTN_SCALE; sA.z*=ATTN_SCALE; sA.w*=ATTN_SCALE;
    sB.x*=ATTN_SCALE; sB.y*=ATTN_SCALE; sB.z*=ATTN_SCALE; sB.w*=ATTN_SCALE;
    float mxA = wred_max(fmaxf(fmaxf(sA.x,sA.y),fmaxf(sA.z,sA.w)));
    float mxB = wred_max(fmaxf(fmaxf(sB.x,sB.y),fmaxf(sB.z,sB.w)));
    float pA0=expf(sA.x-mxA), pA1=expf(sA.y-mxA), pA2=expf(sA.z-mxA), pA3=expf(sA.w-mxA);
    float pB0=expf(sB.x-mxB), pB1=expf(sB.y-mxB), pB2=expf(sB.z-mxB), pB3=expf(sB.w-mxB);
    float invA = 1.f / wred_sum(pA0+pA1+pA2+pA3);
    float invB = 1.f / wred_sum(pB0+pB1+pB2+pB3);
    float aA0=pA0*invA, aA1=pA1*invA, aA2=pA2*invA, aA3=pA3*invA;
    float aB0=pB0*invB, aB1=pB1*invB, aB2=pB2*invB, aB3=pB3*invB;
    float* awA = scratch + h*NN;          // row0 attn weights
    float* awB = scratch + 2048 + h*NN;   // row1
    *(float4*)(awA + j0) = make_float4(aA0,aA1,aA2,aA3);
    *(float4*)(awB + j0) = make_float4(aB0,aB1,aB2,aB3);
    // sc_c = sum_j a_j * edges[i,j,c] per row
    float cA0 = aA0*eL0[(j0+0)*3+0]+aA1*eL0[(j0+1)*3+0]+aA2*eL0[(j0+2)*3+0]+aA3*eL0[(j0+3)*3+0];
    float cA1 = aA0*eL0[(j0+0)*3+1]+aA1*eL0[(j0+1)*3+1]+aA2*eL0[(j0+2)*3+1]+aA3*eL0[(j0+3)*3+1];
    float cA2 = aA0*eL0[(j0+0)*3+2]+aA1*eL0[(j0+1)*3+2]+aA2*eL0[(j0+2)*3+2]+aA3*eL0[(j0+3)*3+2];
    float cB0 = aB0*eL1[(j0+0)*3+0]+aB1*eL1[(j0+1)*3+0]+aB2*eL1[(j0+2)*3+0]+aB3*eL1[(j0+3)*3+0];
    float cB1 = aB0*eL1[(j0+0)*3+1]+aB1*eL1[(j0+1)*3+1]+aB2*eL1[(j0+2)*3+1]+aB3*eL1[(j0+3)*3+1];
    float cB2 = aB0*eL1[(j0+0)*3+2]+aB1*eL1[(j0+1)*3+2]+aB2*eL1[(j0+2)*3+2]+aB3*eL1[(j0+3)*3+2];
    cA0=wred_sum(cA0); cA1=wred_sum(cA1); cA2=wred_sum(cA2);
    cB0=wred_sum(cB0); cB1=wred_sum(cB1); cB2=wred_sum(cB2);
    __builtin_amdgcn_wave_barrier();   // order aW writes before aW reads
    // PV: lane l -> 4 outputs dq..dq+3, j-range jg*64..+63; fold over jg
    const int dq = (l&15)*4, jg = l>>4;
    const float* vb = vg + h*DH + dq;
    float4 accA = make_float4(0.f,0.f,0.f,0.f);
    float4 accB = make_float4(0.f,0.f,0.f,0.f);
#pragma unroll 8
    for(int jj=0; jj<64; jj++){
      int j = jg*64 + jj;
      float aA = awA[j], aB = awB[j];
      float4 vv = *(const float4*)(vb + j*INNER);
      accA.x=fmaf(aA,vv.x,accA.x); accA.y=fmaf(aA,vv.y,accA.y);
      accA.z=fmaf(aA,vv.z,accA.z); accA.w=fmaf(aA,vv.w,accA.w);
      accB.x=fmaf(aB,vv.x,accB.x); accB.y=fmaf(aB,vv.y,accB.y);
      accB.z=fmaf(aB,vv.z,accB.z); accB.w=fmaf(aB,vv.w,accB.w);
    }
#pragma unroll
    for(int o=16;o<64;o<<=1){
      accA.x += __shfl_xor(accA.x,o); accA.y += __shfl_xor(accA.y,o);
      accA.z += __shfl_xor(accA.z,o); accA.w += __shfl_xor(accA.w,o);
      accB.x += __shfl_xor(accB.x,o); accB.y += __shfl_xor(accB.y,o);
      accB.z += __shfl_xor(accB.z,o); accB.w += __shfl_xor(accB.w,o);
    }
    if(l<16){
      float4 we0 = *(const float4*)(We + 0*INNER + h*DH + dq);
      float4 we1 = *(const float4*)(We + 1*INNER + h*DH + dq);
      float4 we2 = *(const float4*)(We + 2*INNER + h*DH + dq);
      float4 oA, oB;
      oA.x = accA.x + cA0*we0.x + cA1*we1.x + cA2*we2.x;
      oA.y = accA.y + cA0*we0.y + cA1*we1.y + cA2*we2.y;
      oA.z = accA.z + cA0*we0.z + cA1*we1.z + cA2*we2.z;
      oA.w = accA.w + cA0*we0.w + cA1*we1.w + cA2*we2.w;
      oB.x = accB.x + cB0*we0.x + cB1*we1.x + cB2*we2.x;
      oB.y = accB.y + cB0*we0.y + cB1*we1.y + cB2*we2.y;
      oB.z = accB.z + cB0*we0.z + cB1*we1.z + cB2*we2.z;
      oB.w = accB.w + cB0*we0.w + cB1*we1.w + cB2*we2.w;
      *(float4*)(ao0 + h*DH + dq) = oA;
      *(float4*)(ao1 + h*DH + dq) = oB;
    }
  }
  __syncthreads();

  // ---- Wo + gate1 ---- (32 col-groups(4) x 16 row-groups(32), both rows)
  {
    const int cg4 = (t&31)*4, rg = t>>5;
    float4 a0 = make_float4(0.f,0.f,0.f,0.f);
    float4 a1 = make_float4(0.f,0.f,0.f,0.f);
#pragma unroll
    for(int r=rg*32; r<rg*32+32; r++){
      float v0 = ao0[r], v1 = ao1[r];
      float4 w = *(const float4*)(Wo + r*DIM + cg4);
      a0.x=fmaf(v0,w.x,a0.x); a0.y=fmaf(v0,w.y,a0.y);
      a0.z=fmaf(v0,w.z,a0.z); a0.w=fmaf(v0,w.w,a0.w);
      a1.x=fmaf(v1,w.x,a1.x); a1.y=fmaf(v1,w.y,a1.y);
      a1.z=fmaf(v1,w.z,a1.z); a1.w=fmaf(v1,w.w,a1.w);
    }
    *(float4*)(scratch + rg*DIM + cg4)        = a0;
    *(float4*)(scratch + 2048 + rg*DIM + cg4) = a1;
    __syncthreads();
    if(t<2*DIM){
      int r = t>>7, c = t&127;
      const float* rs = scratch + r*2048;
      float s = bo[c];
#pragma unroll
      for(int g=0; g<16; g++) s += rs[g*DIM+c];
      (r? o1281 : o1280)[c] = s;
    }
    __syncthreads();
    float gv0=0.f, gv1=0.f;
    if(t<DIM){
      float w0=Wg1[t], w1=Wg1[DIM+t], w2=Wg1[2*DIM+t];
      float oA=o1280[t], rA=nd0[t];
      float oB=o1281[t], rB=nd1[t];
      gv0 = oA*w0 + rA*w1 + (oA-rA)*w2;
      gv1 = oB*w0 + rB*w1 + (oB-rB)*w2;
    }
    float2 gs = block_sum2(gv0, gv1, sred, t);
    float gateA = 1.f/(1.f + expf(-gs.x));
    float gateB = 1.f/(1.f + expf(-gs.y));
    if(t<DIM){
      nd0[t] = o1280[t]*gateA + nd0[t]*(1.f-gateA);
      nd1[t] = o1281[t]*gateB + nd1[t]*(1.f-gateB);
    }
    __syncthreads();
  }

  // ---- LN2 + FFN(gelu exact) + gate2 ----
  dev_ln2(nd0, nd1, xs0, xs1, ln2_g, ln2_b, sred, t);
  {
    const int cg4 = (t&127)*4, rq = t>>7;
    float4 a0 = make_float4(0.f,0.f,0.f,0.f);
    float4 a1 = make_float4(0.f,0.f,0.f,0.f);
#pragma unroll
    for(int f=rq*32; f<rq*32+32; f++){
      float x0 = xs0[f], x1 = xs1[f];
      float4 w = *(const float4*)(W1 + f*INNER + cg4);
      a0.x=fmaf(x0,w.x,a0.x); a0.y=fmaf(x0,w.y,a0.y);
      a0.z=fmaf(x0,w.z,a0.z); a0.w=fmaf(x0,w.w,a0.w);
      a1.x=fmaf(x1,w.x,a1.x); a1.y=fmaf(x1,w.y,a1.y);
      a1.z=fmaf(x1,w.z,a1.z); a1.w=fmaf(x1,w.w,a1.w);
    }
    *(float4*)(scratch + rq*INNER + cg4)        = a0;
    *(float4*)(scratch + 2048 + rq*INNER + cg4) = a1;
  }
  __syncthreads();
  {
    float bt = b1[t];
    float aA = bt + scratch[t] + scratch[INNER+t]
                 + scratch[2*INNER+t] + scratch[3*INNER+t];
    float aB = bt + scratch[2048+t] + scratch[2048+INNER+t]
                 + scratch[2048+2*INNER+t] + scratch[2048+3*INNER+t];
    qs0[t] = 0.5f*aA*(1.f + erff(aA*0.70710678118654752440f));
    qs1[t] = 0.5f*aB*(1.f + erff(aB*0.70710678118654752440f));
  }
  __syncthreads();
  {
    const int cg4 = (t&31)*4, rg = t>>5;
    float4 a0 = make_float4(0.f,0.f,0.f,0.f);
    float4 a1 = make_float4(0.f,0.f,0.f,0.f);
#pragma unroll
    for(int m=rg*32; m<rg*32+32; m++){
      float v0 = qs0[m], v1 = qs1[m];
      float4 w = *(const float4*)(W2 + m*DIM + cg4);
      a0.x=fmaf(v0,w.x,a0.x); a0.y=fmaf(v0,w.y,a0.y);
      a0.z=fmaf(v0,w.z,a0.z); a0.w=fmaf(v0,w.w,a0.w);
      a1.x=fmaf(v1,w.x,a1.x); a1.y=fmaf(v1,w.y,a1.y);
      a1.z=fmaf(v1,w.z,a1.z); a1.w=fmaf(v1,w.w,a1.w);
    }
    *(float4*)(scratch + rg*DIM + cg4)        = a0;
    *(float4*)(scratch + 2048 + rg*DIM + cg4) = a1;
    __syncthreads();
    if(t<2*DIM){
      int r = t>>7, c = t&127;
      const float* rs = scratch + r*2048;
      float s = b2[c];
#pragma unroll
      for(int g=0; g<16; g++) s += rs[g*DIM+c];
      (r? o1281 : o1280)[c] = s;
    }
    __syncthreads();
    float gv0=0.f, gv1=0.f;
    if(t<DIM){
      float w0=Wg2[t], w1=Wg2[DIM+t], w2=Wg2[2*DIM+t];
      float yA=o1280[t], rA=nd0[t];
      float yB=o1281[t], rB=nd1[t];
      gv0 = yA*w0 + rA*w1 + (yA-rA)*w2;
      gv1 = yB*w0 + rB*w1 + (yB-rB)*w2;
    }
    float2 gs = block_sum2(gv0, gv1, sred, t);
    float gateA = 1.f/(1.f + expf(-gs.x));
    float gateB = 1.f/(1.f + expf(-gs.y));
    if(t<DIM){
      nd0[t] = o1280[t]*gateA + nd0[t]*(1.f-gateA);
      nd1[t] = o1281[t]*gateB + nd1[t]*(1.f-gateB);
    }
    __syncthreads();
  }
  if(t<DIM){ nodes[i0*DIM+t] = nd0[t]; nodes[i1*DIM+t] = nd1[t]; }

  // ---- next layer's LN1+QKV (writes the OTHER q/k/v buffer: no race) ----
  if(has_next){
    dev_ln2(nd0, nd1, xs0, xs1, ln1_g_n, ln1_b_n, sred, t);
    dev_qkv2(xs0, xs1, i0, Wq_n, bq_n, Wkv_n, bkv_n, be_n, qg_n, kT_n, vg_n, scratch, t);
  }
}

__global__ __launch_bounds__(64) void k_energy(const float* nodes, const float* out_w,
                                               const float* out_b, float* out){
  int i = blockIdx.x, l = threadIdx.x;
  float a = fmaf(nodes[i*DIM+l], out_w[l], nodes[i*DIM+64+l]*out_w[64+l]);
  a = wred_sum(a);
  if(l==0) out[i] = a + out_b[0];
}

extern "C" void kernel_launch(void* const* d_in, const int* in_sizes, int n_in,
                              void* d_out, int out_size, void* d_ws, size_t ws_size,
                              hipStream_t stream){
  const float* coords   = (const float*)d_in[0];
  const int*   bonds    = (const int*  )d_in[1];
  const float* noise    = (const float*)d_in[2];
  const float* atom_emb = (const float*)d_in[3];
  const float* ln1_g = (const float*)d_in[4];
  const float* ln1_b = (const float*)d_in[5];
  const float* Wq    = (const float*)d_in[6];
  const float* bq    = (const float*)d_in[7];
  const float* Wkv   = (const float*)d_in[8];
  const float* bkv   = (const float*)d_in[9];
  const float* We    = (const float*)d_in[10];
  const float* be    = (const float*)d_in[11];
  const float* Wo    = (const float*)d_in[12];
  const float* bo    = (const float*)d_in[13];
  const float* Wg1   = (const float*)d_in[14];
  const float* ln2_g = (const float*)d_in[15];
  const float* ln2_b = (const float*)d_in[16];
  const float* W1    = (const float*)d_in[17];
  const float* b1    = (const float*)d_in[18];
  const float* W2    = (const float*)d_in[19];
  const float* b2    = (const float*)d_in[20];
  const float* Wg2   = (const float*)d_in[21];
  const float* out_w = (const float*)d_in[22];
  const float* out_b = (const float*)d_in[23];

  // workspace (fp32): ~3.3 MB total
  float* ws = (float*)d_ws;
  float* nodes   = ws;                              // 32768 floats
  float* qbuf[2] = { ws +  32768, ws + 163840 };    // 131072 each
  float* kbuf[2] = { ws + 294912, ws + 425984 };    // transposed [o][j]
  float* vbuf[2] = { ws + 557056, ws + 688128 };    // row-major [j][o]

  k_qkv0<<<128, 512, 0, stream>>>(atom_emb, noise, nodes, ln1_g, ln1_b,
                                  Wq, bq, Wkv, bkv, be,
                                  qbuf[0], kbuf[0], vbuf[0]);
  for(int l=0; l<DEPTH; l++){
    int cur = l&1, nxt = cur^1;
    int has_next = (l < DEPTH-1);
    int ln = has_next ? l+1 : l;    // keep pointers valid when unused
    k_layer<<<128, 512, 0, stream>>>(
      nodes, qbuf[cur], kbuf[cur], vbuf[cur],
      qbuf[nxt], kbuf[nxt], vbuf[nxt],
      bonds, coords,
      We  + (size_t)l*3*INNER,
      Wo  + (size_t)l*INNER*DIM, bo + (size_t)l*DIM, Wg1 + (size_t)l*3*DIM,
      ln2_g + (size_t)l*DIM, ln2_b + (size_t)l*DIM,
      W1  + (size_t)l*DIM*4*DIM, b1 + (size_t)l*4*DIM,
      W2  + (size_t)l*4*DIM*DIM, b2 + (size_t)l*DIM, Wg2 + (size_t)l*3*DIM,
      ln1_g + (size_t)ln*DIM, ln1_b + (size_t)ln*DIM,
      Wq  + (size_t)ln*DIM*INNER, bq + (size_t)ln*INNER,
      Wkv + (size_t)ln*DIM*2*INNER, bkv + (size_t)ln*2*INNER,
      be  + (size_t)ln*INNER, has_next);
  }
  k_energy<<<256, 64, 0, stream>>>(nodes, out_w, out_b, (float*)d_out);
}